// Round 9
// baseline (233.875 us; speedup 1.0000x reference)
//
#include <hip/hip_runtime.h>
#include <hip/hip_bf16.h>
#include <math.h>

#define E_CNT 600000
#define N_CNT 50000
#define H_DIM 128
#define OE_DIM 256

typedef __attribute__((ext_vector_type(8))) short short8;
typedef __attribute__((ext_vector_type(4))) float f32x4;

// ---------------- workspace layout (bytes), all 16-aligned; total ~157 MB
#define WS_OFF    0            // int[N+1]
#define WS_CNT    200016       // int[N]
#define WS_TEXC   400016       // int[50176]
#define WS_BSUM   600720       // int[256]
#define WS_WUP    601744       // ushort[32768]
#define WS_WL1    667280       // ushort[65536]
#define WS_WL2    798352       // ushort[65536]
#define WS_WL3    929424       // ushort[65536]
#define WS_RANK   1060496      // int[E]
#define WS_XE     3460496      // ushort[E*128] = 153.6 MB (CSR-permuted edge feats)

#define SCAN_NB 196            // ceil(50000/256)
#define WCONV_NB 896           // 229376/256

// ---------------------------------------------------------------------------
// Fused: weight shuffle (blocks 0..895) + hist+rank (blocks 896..1919).
// wconv: f32 [O][K] -> bf16 MFMA b-frag order:
//   dst[((ot*KS+ks)*64+lane)*8+j] = W[ot*16+(lane&15)][ks*32+8*(lane>>4)+j]
// hist: rank[e] = running count of node nid[e]  (sequential 2.4MB write);
//       counts[n] = degree. rank makes the prepass atomic-free.
// ---------------------------------------------------------------------------
__global__ __launch_bounds__(256) void histwconv_kernel(
    const int* __restrict__ nid, int* __restrict__ counts,
    int* __restrict__ rank,
    const float* __restrict__ Wup, const float* __restrict__ Wl1,
    const float* __restrict__ Wl2, const float* __restrict__ Wl3,
    ushort* __restrict__ dUp, ushort* __restrict__ dL1,
    ushort* __restrict__ dL2, ushort* __restrict__ dL3)
{
    if (blockIdx.x < WCONV_NB) {
        int d = blockIdx.x * 256 + threadIdx.x;
        const float* W;
        ushort* dst;
        int K;
        if (d < 32768)       { W = Wup; dst = dUp; K = 128; }
        else if (d < 98304)  { d -= 32768;  W = Wl1; dst = dL1; K = 256; }
        else if (d < 163840) { d -= 98304;  W = Wl2; dst = dL2; K = 256; }
        else                 { d -= 163840; W = Wl3; dst = dL3; K = 256; }
        int j = d & 7;
        int l = (d >> 3) & 63;
        int KS = K >> 5;
        int ks = (d >> 9) % KS;
        int ot = (d >> 9) / KS;
        int k = ks * 32 + ((l >> 4) << 3) + j;
        int o = ot * 16 + (l & 15);
        __hip_bfloat16 h = __float2bfloat16(W[o * K + k]);
        dst[d] = *(const ushort*)&h;
    } else {
        int nb = gridDim.x - WCONV_NB;
        for (int e = (blockIdx.x - WCONV_NB) * 256 + threadIdx.x; e < E_CNT;
             e += nb * 256)
            rank[e] = atomicAdd(&counts[nid[e]], 1);
    }
}

// ---------------------------------------------------------------------------
// Coalesced scan (2 kernels): within-tile exclusive, then +block prefix
// ---------------------------------------------------------------------------
__global__ __launch_bounds__(256) void scanA_kernel(const int* __restrict__ counts,
                                                    int* __restrict__ texc,
                                                    int* __restrict__ bsum)
{
    __shared__ int s[256];
    const int t = threadIdx.x;
    const int i = blockIdx.x * 256 + t;
    int v = (i < N_CNT) ? counts[i] : 0;
    s[t] = v;
    __syncthreads();
    for (int off = 1; off < 256; off <<= 1) {
        int u = (t >= off) ? s[t - off] : 0;
        __syncthreads();
        s[t] += u;
        __syncthreads();
    }
    texc[i] = s[t] - v;
    if (t == 255) bsum[blockIdx.x] = s[255];
}

__global__ __launch_bounds__(256) void scanC_kernel(const int* __restrict__ texc,
                                                    const int* __restrict__ bsum,
                                                    int* __restrict__ offs)
{
    __shared__ int red[256];
    const int t = threadIdx.x;
    int v = (t < (int)blockIdx.x && t < SCAN_NB) ? bsum[t] : 0;
    red[t] = v;
    __syncthreads();
    for (int off = 128; off >= 1; off >>= 1) {
        if (t < off) red[t] += red[t + off];
        __syncthreads();
    }
    const int boff = red[0];
    const int i = blockIdx.x * 256 + t;
    if (i < N_CNT) offs[i] = texc[i] + boff;
    if (i == 0) offs[N_CNT] = E_CNT;
}

// ---------------------------------------------------------------------------
// Prepass (atomic-free stream): wave = 4 edges x 16 lanes; lane owns 8 h's.
// slot = offs[nid[e]] + rank[e]  (all plain loads; offs table is L2-hot).
// Reads x/rbf/nid/rank sequentially, scatter-writes 256-B bf16 rows to
// xep[slot] (posted, no return dependency) -> fully pipelineable.
// ---------------------------------------------------------------------------
__global__ __launch_bounds__(256, 4) void prepass_kernel(
    const float* __restrict__ x, const float* __restrict__ rbf,
    const int* __restrict__ nid, const int* __restrict__ rank,
    const int* __restrict__ offs, const float* __restrict__ W_rbf,
    ushort* __restrict__ xep)
{
    const int tid = threadIdx.x;
    const int lane = tid & 63;
    const int q = lane >> 4;            // which of 4 edges
    const int p = lane & 15;            // h-octet
    const int h0 = p * 8;

    float wrb[8][6];
#pragma unroll
    for (int j = 0; j < 8; ++j)
#pragma unroll
        for (int k = 0; k < 6; ++k)
            wrb[j][k] = W_rbf[(h0 + j) * 6 + k];

    const int wid = (blockIdx.x * 256 + tid) >> 6;
    const int nw = (gridDim.x * 256) >> 6;
    const int nquad = E_CNT / 4;        // 150000

    for (int t = wid; t < nquad; t += nw) {
        const int e = t * 4 + q;
        const int slot = offs[nid[e]] + rank[e];

        const float4 xa = *(const float4*)(x + (size_t)e * H_DIM + h0);
        const float4 xb = *(const float4*)(x + (size_t)e * H_DIM + h0 + 4);
        const float2* rp = (const float2*)(rbf + (size_t)e * 6);
        const float2 q0 = rp[0], q1 = rp[1], q2 = rp[2];
        const float r[6] = {q0.x, q0.y, q1.x, q1.y, q2.x, q2.y};

        float c[8];
#pragma unroll
        for (int j = 0; j < 8; ++j) {
            float cc = 0.f;
#pragma unroll
            for (int k = 0; k < 6; ++k) cc = fmaf(r[k], wrb[j][k], cc);
            c[j] = cc;
        }
        const float xv[8] = {xa.x, xa.y, xa.z, xa.w, xb.x, xb.y, xb.z, xb.w};
        ushort pk[8];
#pragma unroll
        for (int j = 0; j < 8; ++j) {
            __hip_bfloat16 h = __float2bfloat16(c[j] * xv[j]);
            pk[j] = *(const ushort*)&h;
        }
        *(int4*)(xep + (size_t)slot * H_DIM + h0) = *(const int4*)pk;
    }
}

// ---------------------------------------------------------------------------
// Fused seq-gather + MFMA MLP. 32 nodes/block, 512 threads (8 waves).
// Gather: wave w owns nodes 4w..4w+3; slots contiguous in xep -> coalesced
// 1KB reads, affine addresses. Reduce across slot-groups via shfl_xor(16/32).
// Then ping-pong MFMA MLP.
// mfma_f32_16x16x32_bf16: a[lane l][j]=A[l&15][8*(l>>4)+j];
// D[lane l][r]=out[4*(l>>4)+r][l&15] (m89-verified).
// ---------------------------------------------------------------------------
#define MB 32
#define PITCH 264

template<int KS, bool SW>
__device__ __forceinline__ void layer(const ushort* __restrict__ Wsh,
                                      const float* __restrict__ bias,
                                      const ushort* in_s, ushort* out_s, int tid)
{
    const int w = tid >> 6, lane = tid & 63;
    const int l15 = lane & 15, lg = lane >> 4;

    f32x4 acc[2][2];
#pragma unroll
    for (int mi = 0; mi < 2; ++mi)
#pragma unroll
        for (int oi = 0; oi < 2; ++oi)
            acc[mi][oi] = (f32x4){0.f, 0.f, 0.f, 0.f};

#pragma unroll
    for (int ks = 0; ks < KS; ++ks) {
        short8 b0 = *(const short8*)(Wsh + (size_t)(((w * 2 + 0) * KS + ks) * 64 + lane) * 8);
        short8 b1 = *(const short8*)(Wsh + (size_t)(((w * 2 + 1) * KS + ks) * 64 + lane) * 8);
#pragma unroll
        for (int mi = 0; mi < 2; ++mi) {
            short8 a = *(const short8*)(in_s + (mi * 16 + l15) * PITCH + ks * 32 + lg * 8);
            acc[mi][0] = __builtin_amdgcn_mfma_f32_16x16x32_bf16(a, b0, acc[mi][0], 0, 0, 0);
            acc[mi][1] = __builtin_amdgcn_mfma_f32_16x16x32_bf16(a, b1, acc[mi][1], 0, 0, 0);
        }
    }

#pragma unroll
    for (int oi = 0; oi < 2; ++oi) {
        float bv = bias[(w * 2 + oi) * 16 + l15];
#pragma unroll
        for (int mi = 0; mi < 2; ++mi)
#pragma unroll
            for (int r = 0; r < 4; ++r) {
                float v = acc[mi][oi][r] + bv;
                if (SW) v = v / (1.f + __expf(-v));
                __hip_bfloat16 h = __float2bfloat16(v);
                out_s[(mi * 16 + lg * 4 + r) * PITCH + (w * 2 + oi) * 16 + l15] =
                    *(const ushort*)&h;
            }
    }
}

__global__ __launch_bounds__(512, 6) void fused_kernel(
    const ushort* __restrict__ xep,
    const int* __restrict__ offs,
    const float* __restrict__ W_w, const float* __restrict__ b_w,
    const ushort* __restrict__ Wup, const ushort* __restrict__ Wl1,
    const ushort* __restrict__ Wl2, const ushort* __restrict__ Wl3,
    const float* __restrict__ b_up, const float* __restrict__ b_l1,
    const float* __restrict__ b_l2, const float* __restrict__ b_l3,
    const float* __restrict__ W_out, const int* __restrict__ batch,
    float* __restrict__ out)
{
    __shared__ ushort sA[MB * PITCH];       // 16.9 KB
    __shared__ ushort sB[MB * PITCH];       // 16.9 KB
    __shared__ int s_off[MB + 1];
    __shared__ float s_alpha[MB];

    const int tid = threadIdx.x;
    const int w = tid >> 6, lane = tid & 63;
    const int node0 = blockIdx.x * MB;

    // fold-in: batch -> out[N..2N)
    if (tid < MB) {
        int node = node0 + tid;
        if (node < N_CNT) out[N_CNT + node] = (float)batch[node];
    }
    if (tid < MB + 1)
        s_off[tid] = offs[min(node0 + tid, N_CNT)];
    __syncthreads();

    // ---- gather phase: wave w owns nodes 4w..4w+3; sequential slot reads
    {
        const int eq = lane >> 4;           // slot offset within quad
        const int p = lane & 15;            // 8-h segment
        float ww[8];
#pragma unroll
        for (int j = 0; j < 8; ++j) ww[j] = W_w[p * 8 + j];
        const float bw = b_w[0];

        for (int nl4 = 0; nl4 < 4; ++nl4) {
            const int nl = (w << 2) + nl4;
            const int ls = s_off[nl], le = s_off[nl + 1];
            float acc[8];
#pragma unroll
            for (int j = 0; j < 8; ++j) acc[j] = 0.f;

#pragma unroll 2
            for (int s = ls + eq; s < le; s += 4) {
                short8 rv = *(const short8*)(xep + (size_t)s * H_DIM + p * 8);
#pragma unroll
                for (int j = 0; j < 8; ++j) {
                    ushort u = (ushort)rv[j];
                    acc[j] += __bfloat162float(*(const __hip_bfloat16*)&u);
                }
            }
            // reduce across the 4 slot groups
#pragma unroll
            for (int j = 0; j < 8; ++j) {
                acc[j] += __shfl_xor(acc[j], 16);
                acc[j] += __shfl_xor(acc[j], 32);
            }
            // alpha
            float part = 0.f;
#pragma unroll
            for (int j = 0; j < 8; ++j) part = fmaf(acc[j], ww[j], part);
            part += __shfl_xor(part, 1);
            part += __shfl_xor(part, 2);
            part += __shfl_xor(part, 4);
            part += __shfl_xor(part, 8);
            if (lane == 0) s_alpha[nl] = part + bw;
            // write row (bf16) into MFMA A-tile
            if (eq == 0) {
                ushort pk[8];
#pragma unroll
                for (int j = 0; j < 8; ++j) {
                    __hip_bfloat16 h = __float2bfloat16(acc[j]);
                    pk[j] = *(const ushort*)&h;
                }
                *(int4*)(sA + nl * PITCH + p * 8) = *(const int4*)pk;
            }
        }
    }
    __syncthreads();

    // ---- MLP phase (ping-pong, 1 barrier per layer)
    layer<4, false>(Wup, b_up, sA, sB, tid);
    __syncthreads();
    layer<8, true>(Wl1, b_l1, sB, sA, tid);
    __syncthreads();
    layer<8, true>(Wl2, b_l2, sA, sB, tid);
    __syncthreads();
    layer<8, true>(Wl3, b_l3, sB, sA, tid);
    __syncthreads();

    // out[n] = (x2[n,:] . W_out) * alpha[n]; 16 threads per node, 16 o's each
    {
        int nl = tid >> 4, q = tid & 15;
        const ushort* rowp = sA + nl * PITCH + q * 16;
        float sum = 0.f;
#pragma unroll
        for (int o = 0; o < 16; ++o) {
            __hip_bfloat16 h = *(const __hip_bfloat16*)(rowp + o);
            sum = fmaf(__bfloat162float(h), W_out[q * 16 + o], sum);
        }
        sum += __shfl_xor(sum, 1);
        sum += __shfl_xor(sum, 2);
        sum += __shfl_xor(sum, 4);
        sum += __shfl_xor(sum, 8);
        int node = node0 + nl;
        if (q == 0 && node < N_CNT) out[node] = sum * s_alpha[nl];
    }
}

extern "C" void kernel_launch(void* const* d_in, const int* in_sizes, int n_in,
                              void* d_out, int out_size, void* d_ws, size_t ws_size,
                              hipStream_t stream)
{
    const float* x      = (const float*)d_in[0];
    const float* rbf    = (const float*)d_in[1];
    const int*   nid    = (const int*)d_in[2];
    const int*   batch  = (const int*)d_in[5];
    const float* W_rbf  = (const float*)d_in[7];
    const float* W_up   = (const float*)d_in[8];
    const float* b_up   = (const float*)d_in[9];
    const float* W_l1   = (const float*)d_in[10];
    const float* b_l1   = (const float*)d_in[11];
    const float* W_l2   = (const float*)d_in[12];
    const float* b_l2   = (const float*)d_in[13];
    const float* W_l3   = (const float*)d_in[14];
    const float* b_l3   = (const float*)d_in[15];
    const float* W_out  = (const float*)d_in[16];
    const float* W_w    = (const float*)d_in[17];
    const float* b_w    = (const float*)d_in[18];

    char* ws = (char*)d_ws;
    int*    offs   = (int*)(ws + WS_OFF);
    int*    counts = (int*)(ws + WS_CNT);
    int*    texc   = (int*)(ws + WS_TEXC);
    int*    bsum   = (int*)(ws + WS_BSUM);
    ushort* WupS   = (ushort*)(ws + WS_WUP);
    ushort* Wl1S   = (ushort*)(ws + WS_WL1);
    ushort* Wl2S   = (ushort*)(ws + WS_WL2);
    ushort* Wl3S   = (ushort*)(ws + WS_WL3);
    int*    rank   = (int*)(ws + WS_RANK);
    ushort* xep    = (ushort*)(ws + WS_XE);
    float*  out    = (float*)d_out;

    hipMemsetAsync(counts, 0, N_CNT * sizeof(int), stream);
    histwconv_kernel<<<WCONV_NB + 1024, 256, 0, stream>>>(
        nid, counts, rank, W_up, W_l1, W_l2, W_l3, WupS, Wl1S, Wl2S, Wl3S);
    scanA_kernel<<<SCAN_NB, 256, 0, stream>>>(counts, texc, bsum);
    scanC_kernel<<<SCAN_NB, 256, 0, stream>>>(texc, bsum, offs);

    prepass_kernel<<<2048, 256, 0, stream>>>(x, rbf, nid, rank, offs, W_rbf, xep);

    fused_kernel<<<(N_CNT + MB - 1) / MB, 512, 0, stream>>>(
        xep, offs, W_w, b_w,
        WupS, Wl1S, Wl2S, Wl3S, b_up, b_l1, b_l2, b_l3, W_out, batch, out);
}